// Round 26
// baseline (607.899 us; speedup 1.0000x reference)
//
#include <hip/hip_runtime.h>
#include <math.h>

typedef __attribute__((ext_vector_type(8))) short bf16x8;   // 8 bf16 (4 VGPRs)
typedef __attribute__((ext_vector_type(4))) float f32x4;

// ---------------- workspace layout (bytes) ----------------
constexpr size_t XW_OFF  = 0;                                   // 96 MB (gemm out; read by gru; dead after gru2)
constexpr size_t O1_OFF  = XW_OFF + 65536ull * 384 * 4;
constexpr size_t O2_OFF  = O1_OFF + 512ull * 128 * 128 * 4;
constexpr size_t Y0_OFF  = O2_OFF + 512ull * 128 * 128 * 4;
constexpr size_t Y1_OFF  = Y0_OFF + 256ull * 128 * 4;
constexpr size_t MMD_OFF = Y1_OFF + 256ull * 128 * 4;
constexpr size_t WTS_OFF = MMD_OFF + 256 * 4;
constexpr size_t BW_OFF  = WTS_OFF + 256 * 4;
constexpr size_t WBF_OFF = BW_OFF + 4096;                       // 8 bf16 weight slots = 768 KB
// aliases inside dead xw region (valid after gru2; prep runs in fat2):
constexpr size_t NRM_OFF = XW_OFF;
constexpr size_t CHI_OFF = XW_OFF + (1ull << 20);
constexpr size_t CLO_OFF = CHI_OFF + 36ull * 1024 * 1024;

static __device__ __forceinline__ unsigned short f2bf(float x) {
    unsigned u = __float_as_uint(x);
    unsigned r = (u + 0x7FFFu + ((u >> 16) & 1u)) >> 16;
    return (unsigned short)r;
}
static __device__ __forceinline__ float bf2f(unsigned short b) {
    return __uint_as_float((unsigned)b << 16);
}
static __device__ __forceinline__ void cvt8(const float* __restrict__ p,
                                            bf16x8* hi, bf16x8* lo) {
    float4 v0 = *(const float4*)p;
    float4 v1 = *(const float4*)(p + 4);
    union { unsigned short us[8]; bf16x8 v; } H, L;
    float f[8] = {v0.x, v0.y, v0.z, v0.w, v1.x, v1.y, v1.z, v1.w};
#pragma unroll
    for (int i = 0; i < 8; ++i) {
        H.us[i] = f2bf(f[i]);
        L.us[i] = f2bf(f[i] - bf2f(H.us[i]));
    }
    *hi = H.v; *lo = L.v;
}

// ---------------- cvt_w4 ----------------
__global__ __launch_bounds__(256) void cvt_w4(const float* __restrict__ W0, const float* __restrict__ W1,
                                              const float* __restrict__ W2, const float* __restrict__ W3,
                                              unsigned short* __restrict__ H0, unsigned short* __restrict__ L0,
                                              unsigned short* __restrict__ H1, unsigned short* __restrict__ L1,
                                              unsigned short* __restrict__ H2, unsigned short* __restrict__ L2,
                                              unsigned short* __restrict__ H3, unsigned short* __restrict__ L3)
{
    const int which = blockIdx.y;
    const float* W = (which == 0) ? W0 : (which == 1) ? W1 : (which == 2) ? W2 : W3;
    unsigned short* whi = (which == 0) ? H0 : (which == 1) ? H1 : (which == 2) ? H2 : H3;
    unsigned short* wlo = (which == 0) ? L0 : (which == 1) ? L1 : (which == 2) ? L2 : L3;
    int f = blockIdx.x * 256 + threadIdx.x;
    if (f >= 12288) return;
    float4 v = ((const float4*)W)[f];
    ushort4 uh, ul;
    uh.x = f2bf(v.x); ul.x = f2bf(v.x - bf2f(uh.x));
    uh.y = f2bf(v.y); ul.y = f2bf(v.y - bf2f(uh.y));
    uh.z = f2bf(v.z); ul.z = f2bf(v.z - bf2f(uh.z));
    uh.w = f2bf(v.w); ul.w = f2bf(v.w - bf2f(uh.w));
    *(ushort4*)(whi + 4 * f) = uh;
    *(ushort4*)(wlo + 4 * f) = ul;
}

// ---------------- gemm: C[M][384] = A_f32 @ W^T + bias ----------------
__global__ __launch_bounds__(256) void gemm_f32a(const float* __restrict__ A,
                                                 const unsigned short* __restrict__ whi,
                                                 const unsigned short* __restrict__ wlo,
                                                 const float* __restrict__ bias,
                                                 float* __restrict__ C)
{
    const int m0 = blockIdx.x * 128;
    const int n0 = blockIdx.y * 128;
    const int tid  = threadIdx.x;
    const int lane = tid & 63;
    const int wave = tid >> 6;
    const int wm = wave >> 1, wn = wave & 1;
    const int r16 = lane & 15;
    const int kq  = lane >> 4;

    const int arow = m0 + wm * 64 + r16;
    const int brow = n0 + wn * 64 + r16;

    f32x4 acc[4][4];
#pragma unroll
    for (int mf = 0; mf < 4; ++mf)
#pragma unroll
        for (int nf = 0; nf < 4; ++nf) acc[mf][nf] = (f32x4){0.f, 0.f, 0.f, 0.f};

#pragma unroll 1
    for (int kc = 0; kc < 128; kc += 32) {
        const int koff = kc + 8 * kq;
        bf16x8 ah[4], al[4], bh[4], bl[4];
#pragma unroll
        for (int mf = 0; mf < 4; ++mf)
            cvt8(A + (size_t)(arow + mf * 16) * 128 + koff, &ah[mf], &al[mf]);
#pragma unroll
        for (int nf = 0; nf < 4; ++nf) {
            size_t off = (size_t)(brow + nf * 16) * 128 + koff;
            bh[nf] = *(const bf16x8*)(whi + off);
            bl[nf] = *(const bf16x8*)(wlo + off);
        }
#pragma unroll
        for (int mf = 0; mf < 4; ++mf)
#pragma unroll
            for (int nf = 0; nf < 4; ++nf) {
                acc[mf][nf] = __builtin_amdgcn_mfma_f32_16x16x32_bf16(ah[mf], bh[nf], acc[mf][nf], 0, 0, 0);
                acc[mf][nf] = __builtin_amdgcn_mfma_f32_16x16x32_bf16(ah[mf], bl[nf], acc[mf][nf], 0, 0, 0);
                acc[mf][nf] = __builtin_amdgcn_mfma_f32_16x16x32_bf16(al[mf], bh[nf], acc[mf][nf], 0, 0, 0);
            }
    }

    float nb[4];
#pragma unroll
    for (int nf = 0; nf < 4; ++nf) nb[nf] = bias[n0 + wn * 64 + nf * 16 + r16];

#pragma unroll
    for (int mf = 0; mf < 4; ++mf)
#pragma unroll
        for (int nf = 0; nf < 4; ++nf)
#pragma unroll
            for (int r = 0; r < 4; ++r) {
                int row = m0 + wm * 64 + mf * 16 + kq * 4 + r;
                int col = n0 + wn * 64 + nf * 16 + r16;
                C[(size_t)row * 384 + col] = acc[mf][nf][r] + nb[nf];
            }
}

// ---------------- GRU macros: single-bf16 h AND single-bf16 whh ----------------
#define GRU_BODY(STCUR, CUR, XR, XZ, XN)                                              \
    {                                                                                 \
        bf16x8 Bh[4];                                                                 \
        _Pragma("unroll")                                                             \
        for (int c = 0; c < 4; ++c) {                                                 \
            int rslot = (b * 128 + 32 * c + 8 * kq) ^ ((b & 7) << 3);                 \
            Bh[c] = *(const bf16x8*)&hb[CUR][rslot];                                  \
        }                                                                             \
        f32x4 acc[3];                                                                 \
        _Pragma("unroll")                                                             \
        for (int g = 0; g < 3; ++g) acc[g] = (f32x4){0.f, 0.f, 0.f, 0.f};             \
        _Pragma("unroll")                                                             \
        for (int c = 0; c < 4; ++c)                                                   \
            _Pragma("unroll")                                                         \
            for (int g = 0; g < 3; ++g)                                               \
                acc[g] = __builtin_amdgcn_mfma_f32_16x16x32_bf16(Ah[g][c], Bh[c], acc[g], 0, 0, 0); \
        f32x4 hnew;                                                                   \
        ushort4 nhi;                                                                  \
        _Pragma("unroll")                                                             \
        for (int r = 0; r < 4; ++r) {                                                 \
            float rr = 1.f / (1.f + __expf(-(XR[r] + acc[0][r] + bh[0][r])));         \
            float zz = 1.f / (1.f + __expf(-(XZ[r] + acc[1][r] + bh[1][r])));         \
            float xa = XN[r] + rr * (acc[2][r] + bh[2][r]);                           \
            float ex = __expf(-2.f * fabsf(xa));                                      \
            float th = (1.f - ex) / (1.f + ex);                                       \
            th = copysignf(th, xa);                                                   \
            hnew[r] = (1.f - zz) * th + zz * hold[r];                                 \
        }                                                                             \
        hold = hnew;                                                                  \
        nhi.x = f2bf(hnew[0]);                                                        \
        nhi.y = f2bf(hnew[1]);                                                        \
        nhi.z = f2bf(hnew[2]);                                                        \
        nhi.w = f2bf(hnew[3]);                                                        \
        *(ushort4*)&hb[(CUR) ^ 1][wslot] = nhi;                                       \
        *(f32x4*)(outp + ((size_t)B * 128 + (STCUR)) * 128 + u0) = hnew;              \
        {                                                                             \
            const int ld = ((STCUR) + 2 < 128) ? (STCUR) + 2 : 127;                   \
            XR = *(const f32x4*)(xb + ld * 384 + u0);                                 \
            XZ = *(const f32x4*)(xb + ld * 384 + 128 + u0);                           \
            XN = *(const f32x4*)(xb + ld * 384 + 256 + u0);                           \
        }                                                                             \
        asm volatile("s_waitcnt lgkmcnt(0)" ::: "memory");                            \
        __builtin_amdgcn_s_barrier();                                                 \
    }

#define GRU_PROLOGUE(BLK, WHI, BHH, XW)                                               \
    const int tid  = threadIdx.x;                                                     \
    const int w    = tid >> 6;                                                        \
    const int lane = tid & 63;                                                        \
    const int b    = lane & 15;                                                       \
    const int kq   = lane >> 4;                                                       \
    const int u0   = 16 * w + 4 * kq;                                                 \
    const int B    = (BLK) * 16 + b;                                                  \
    bf16x8 Ah[3][4];                                                                  \
    _Pragma("unroll")                                                                 \
    for (int g = 0; g < 3; ++g)                                                       \
        _Pragma("unroll")                                                             \
        for (int c = 0; c < 4; ++c) {                                                 \
            size_t off = (size_t)(128 * g + 16 * w + b) * 128 + 32 * c + 8 * kq;      \
            Ah[g][c] = *(const bf16x8*)((WHI) + off);                                 \
        }                                                                             \
    f32x4 bh[3];                                                                      \
    _Pragma("unroll")                                                                 \
    for (int g = 0; g < 3; ++g) bh[g] = *(const f32x4*)((BHH) + 128 * g + u0);        \
    const int wslot = (b * 128 + u0) ^ ((b & 7) << 3);                                \
    *(ushort4*)&hb[0][wslot] = (ushort4){0, 0, 0, 0};                                 \
    __syncthreads();                                                                  \
    f32x4 hold = (f32x4){0.f, 0.f, 0.f, 0.f};                                         \
    const float* xb = (XW) + (size_t)B * 128 * 384;                                   \
    f32x4 xAr = *(const f32x4*)(xb + u0);                                             \
    f32x4 xAz = *(const f32x4*)(xb + 128 + u0);                                       \
    f32x4 xAn = *(const f32x4*)(xb + 256 + u0);                                       \
    f32x4 xBr = *(const f32x4*)(xb + 384 + u0);                                       \
    f32x4 xBz = *(const f32x4*)(xb + 384 + 128 + u0);                                 \
    f32x4 xBn = *(const f32x4*)(xb + 384 + 256 + u0);

// ---------------- GRU layer 1 ----------------
__global__ __launch_bounds__(512, 1) void gru_mfma(const float* __restrict__ xw,
                                                   const unsigned short* __restrict__ whi,
                                                   const float* __restrict__ bhh,
                                                   float* __restrict__ outp)
{
    __shared__ __align__(16) unsigned short hb[2][2048];
    GRU_PROLOGUE(blockIdx.x, whi, bhh, xw)
#pragma unroll 1
    for (int st = 0; st < 128; st += 2) {
        GRU_BODY(st,     0, xAr, xAz, xAn)
        GRU_BODY(st + 1, 1, xBr, xBz, xBn)
    }
}

// ---------------- bodies ----------------
static __device__ __forceinline__ void gate_gemm_body(const float* __restrict__ o,
                                                      const float* __restrict__ gw,
                                                      float* __restrict__ y,
                                                      int gx, int gy, int gz,
                                                      float (*As)[36], float (*Ws)[36])
{
    const int tid = threadIdx.x;
    const int tx = tid & 15, ty = (tid >> 4) & 31;
    const int m0 = gx * 64, n0 = gy * 64;
    const int k0beg = gz * 1024;

    float acc[2][4];
#pragma unroll
    for (int i = 0; i < 2; ++i)
#pragma unroll
        for (int j = 0; j < 4; ++j) acc[i][j] = 0.f;

#pragma unroll 1
    for (int kc = k0beg; kc < k0beg + 1024; kc += 32) {
        {
            int row = tid >> 3;
            int c4  = (tid & 7) * 4;
            int kap = kc + c4;
            int s = kap >> 8, half = (kap >> 7) & 1, h = kap & 127;
            float4 va = *(const float4*)(o + ((size_t)(m0 + row + 256 * half) * 128 + s) * 128 + h);
            *(float4*)&As[row][c4] = va;
            float4 vw = *(const float4*)(gw + (size_t)(n0 + row) * 32768 + kap);
            *(float4*)&Ws[row][c4] = vw;
        }
        __syncthreads();
#pragma unroll 1
        for (int k0 = 0; k0 < 32; k0 += 4) {
            float4 a4[2], w4[4];
#pragma unroll
            for (int i = 0; i < 2; ++i) a4[i] = *(float4*)&As[ty + 32 * i][k0];
#pragma unroll
            for (int j = 0; j < 4; ++j) w4[j] = *(float4*)&Ws[tx + 16 * j][k0];
#pragma unroll
            for (int i = 0; i < 2; ++i)
#pragma unroll
                for (int j = 0; j < 4; ++j) {
                    acc[i][j] += a4[i].x * w4[j].x + a4[i].y * w4[j].y +
                                 a4[i].z * w4[j].z + a4[i].w * w4[j].w;
                }
        }
        __syncthreads();
    }
#pragma unroll
    for (int i = 0; i < 2; ++i)
#pragma unroll
        for (int j = 0; j < 4; ++j) {
            int r = m0 + ty + 32 * i, c = n0 + tx + 16 * j;
            atomicAdd(&y[r * 128 + c], acc[i][j]);
        }
}

static __device__ __forceinline__ void pair_stats_body(const float* __restrict__ o, int s,
                                                       float* __restrict__ bwp,
                                                       float* u2, float* red)
{
    const int tid = threadIdx.x;
    const int h = tid & 127, q = tid >> 7;

    float acc_u = 0.f, acc_sq = 0.f;
    for (int r = 0; r < 128; ++r) {
        int i = q * 128 + r;
        float v = o[((size_t)i * 128 + s) * 128 + h];
        acc_u += v; acc_sq += v * v;
    }
    u2[tid] = acc_u;
    red[tid] = acc_sq;
    __syncthreads();
    for (int st = 256; st > 0; st >>= 1) {
        if (tid < st) red[tid] += red[tid + st];
        __syncthreads();
    }
    float S1 = red[0];
    __syncthreads();
    float uu = 0.f;
    if (tid < 128) {
        float t = u2[tid] + u2[tid + 128] + u2[tid + 256] + u2[tid + 384];
        uu = t * t;
    }
    red[tid] = (tid < 128) ? uu : 0.f;
    __syncthreads();
    for (int st = 64; st > 0; st >>= 1) {
        if (tid < st) red[tid] += red[tid + st];
        __syncthreads();
    }
    if (tid == 0) {
        float S2 = red[0];
        float d2s = 1024.f * S1 - 2.f * S2;
        *bwp = d2s / (512.f * 512.f - 512.f) * 0.25f;
    }
}

static __device__ __forceinline__ void prep_body(const float* __restrict__ o, int s, int l,
                                                 unsigned short* __restrict__ chi,
                                                 unsigned short* __restrict__ clo,
                                                 float* __restrict__ norms)
{
    const int t = threadIdx.x;
    const int h4 = (t & 31) * 4;
    const size_t pb = ((size_t)l * 128 + s) * 512 * 128;
    float* np_ = norms + ((size_t)l * 128 + s) * 512;
#pragma unroll 1
    for (int i = t >> 5; i < 512; i += 16) {
        float4 v = *(const float4*)(o + ((size_t)i * 128 + s) * 128 + h4);
        ushort4 uh, ul;
        uh.x = f2bf(v.x); ul.x = f2bf(v.x - bf2f(uh.x));
        uh.y = f2bf(v.y); ul.y = f2bf(v.y - bf2f(uh.y));
        uh.z = f2bf(v.z); ul.z = f2bf(v.z - bf2f(uh.z));
        uh.w = f2bf(v.w); ul.w = f2bf(v.w - bf2f(uh.w));
        *(ushort4*)(chi + pb + (size_t)i * 128 + h4) = uh;
        *(ushort4*)(clo + pb + (size_t)i * 128 + h4) = ul;
        float sq = v.x * v.x + v.y * v.y + v.z * v.z + v.w * v.w;
        sq += __shfl_xor(sq, 1);
        sq += __shfl_xor(sq, 2);
        sq += __shfl_xor(sq, 4);
        sq += __shfl_xor(sq, 8);
        sq += __shfl_xor(sq, 16);
        if ((t & 31) == 0) np_[i] = sq;
    }
}

static __device__ __forceinline__ void fc_body(int bid0, const float* __restrict__ o2,
                                               const float* __restrict__ fcw,
                                               const float* __restrict__ fcb,
                                               float* __restrict__ outp)
{
    int gid = bid0 * 512 + threadIdx.x;
    if (gid < 3072) {
        int b = gid / 6, oo = gid - b * 6;
        const float* xr = o2 + ((size_t)b * 128 + 127) * 128;
        const float* wr = fcw + oo * 128;
        float acc = fcb[oo];
#pragma unroll 16
        for (int k = 0; k < 128; ++k) acc += xr[k] * wr[k];
        outp[gid] = acc;
    }
}

static __device__ __forceinline__ void mmd_body(const unsigned short* __restrict__ chi,
                                                const unsigned short* __restrict__ clo,
                                                const float* __restrict__ norms,
                                                const float* __restrict__ bw,
                                                float* __restrict__ mmdv,
                                                int p, int tp, float* rbuf)
{
    int ti, tj;
    if (tp < 4)      { ti = 0; tj = tp; }
    else if (tp < 7) { ti = 1; tj = tp - 3; }
    else if (tp < 9) { ti = 2; tj = tp - 5; }
    else             { ti = 3; tj = 3; }
    const float sgn  = ((ti < 2) == (tj < 2)) ? 1.f : -1.f;
    const float coef = sgn * ((ti == tj) ? 1.f : 2.f);

    const int tid  = threadIdx.x;
    const int lane = tid & 63;
    const int wave = tid >> 6;
    const int wm = wave >> 1, wn = wave & 1;
    const int r16 = lane & 15;
    const int kq  = lane >> 4;

    const size_t pbase = (size_t)p * 512 * 128;
    const int arow = ti * 128 + wm * 64 + r16;
    const int brow = tj * 128 + wn * 64 + r16;

    f32x4 acc[4][4];
#pragma unroll
    for (int mf = 0; mf < 4; ++mf)
#pragma unroll
        for (int nf = 0; nf < 4; ++nf) acc[mf][nf] = (f32x4){0.f, 0.f, 0.f, 0.f};

#pragma unroll 1
    for (int kc = 0; kc < 128; kc += 32) {
        const size_t koff = (size_t)kc + 8 * kq;
        bf16x8 ah[4], al[4], bh[4], bl[4];
#pragma unroll
        for (int mf = 0; mf < 4; ++mf) {
            size_t off = pbase + (size_t)(arow + mf * 16) * 128 + koff;
            ah[mf] = *(const bf16x8*)(chi + off);
            al[mf] = *(const bf16x8*)(clo + off);
        }
#pragma unroll
        for (int nf = 0; nf < 4; ++nf) {
            size_t off = pbase + (size_t)(brow + nf * 16) * 128 + koff;
            bh[nf] = *(const bf16x8*)(chi + off);
            bl[nf] = *(const bf16x8*)(clo + off);
        }
#pragma unroll
        for (int mf = 0; mf < 4; ++mf)
#pragma unroll
            for (int nf = 0; nf < 4; ++nf) {
                acc[mf][nf] = __builtin_amdgcn_mfma_f32_16x16x32_bf16(ah[mf], bh[nf], acc[mf][nf], 0, 0, 0);
                acc[mf][nf] = __builtin_amdgcn_mfma_f32_16x16x32_bf16(ah[mf], bl[nf], acc[mf][nf], 0, 0, 0);
                acc[mf][nf] = __builtin_amdgcn_mfma_f32_16x16x32_bf16(al[mf], bh[nf], acc[mf][nf], 0, 0, 0);
            }
    }

    const float* np_ = norms + (size_t)p * 512;
    float na[4][4], nb[4];
#pragma unroll
    for (int mf = 0; mf < 4; ++mf)
#pragma unroll
        for (int r = 0; r < 4; ++r)
            na[mf][r] = np_[ti * 128 + wm * 64 + mf * 16 + (lane >> 4) * 4 + r];
#pragma unroll
    for (int nf = 0; nf < 4; ++nf)
        nb[nf] = np_[tj * 128 + wn * 64 + nf * 16 + (lane & 15)];

    const float bwv = bw[p];
    const float c4 = -1.f / (bwv * 16.f);
    float tot = 0.f;
#pragma unroll
    for (int mf = 0; mf < 4; ++mf)
#pragma unroll
        for (int nf = 0; nf < 4; ++nf)
#pragma unroll
            for (int r = 0; r < 4; ++r) {
                float d2 = na[mf][r] + nb[nf] - 2.f * acc[mf][nf][r];
                float e4 = __expf(c4 * d2);
                float e3 = e4 * e4;
                float e2 = e3 * e3;
                float e1 = e2 * e2;
                float e0 = e1 * e1;
                tot += ((e0 + e1) + (e2 + e3)) + e4;
            }
    tot *= coef;

    for (int off = 32; off > 0; off >>= 1) tot += __shfl_down(tot, off);
    if ((tid & 63) == 0) rbuf[tid >> 6] = tot;
    __syncthreads();
    if (tid == 0) atomicAdd(&mmdv[p], rbuf[0] + rbuf[1] + rbuf[2] + rbuf[3]);
}

static __device__ __forceinline__ void gate_reduce_body(const float* __restrict__ y,
                                                        const float* __restrict__ gamma,
                                                        const float* __restrict__ beta,
                                                        float* __restrict__ ws_p,
                                                        float* __restrict__ out_p,
                                                        float* red)
{
    const int o = threadIdx.x;
    const bool act = (o < 128);
    float wo = 0.f;
    if (act) {
        float sum = 0.f, sumsq = 0.f;
        for (int b = 0; b < 256; ++b) {
            float v = y[b * 128 + o];
            sum += v; sumsq += v * v;
        }
        float m = sum * (1.f / 256.f);
        float var = sumsq * (1.f / 256.f) - m * m;
        float inv = rsqrtf(var + 1e-5f);
        float g = gamma[o], be = beta[o];
        float sw = 0.f;
        for (int b = 0; b < 256; ++b) {
            float v = y[b * 128 + o];
            float t = g * (v - m) * inv + be;
            sw += 1.f / (1.f + __expf(-t));
        }
        wo = sw * (1.f / 256.f);
        red[o] = wo;
    }
    __syncthreads();
    for (int st = 64; st > 0; st >>= 1) {
        if (act && o < st) red[o] = fmaxf(red[o], red[o + st]);
        __syncthreads();
    }
    float mx = red[0];
    __syncthreads();
    float e = act ? __expf(wo - mx) : 0.f;
    if (act) red[o] = e;
    __syncthreads();
    for (int st = 64; st > 0; st >>= 1) {
        if (act && o < st) red[o] += red[o + st];
        __syncthreads();
    }
    if (act) {
        float r = e / red[0];
        ws_p[o] = r;
        out_p[o] = r;
    }
}

// ---------------- FAT1: gru2 (0..31, prio 1) || gate_gemm0 (32..287) || pair_stats l0 (288..415) ----------------
// LDS padded past 80 KB -> 1 block/CU: no gate/pair block can co-schedule on a
// gru CU (R24/R25 showed co-residency stole issue slots from the serial gru chain;
// setprio alone was null). Gate blocks run on the other 224 CUs in 2 rounds,
// still hidden under gru2's runtime.
__global__ __launch_bounds__(512, 1) void fat1(const float* __restrict__ xw,
                                               const unsigned short* __restrict__ whi,
                                               const float* __restrict__ bhh,
                                               float* __restrict__ o2,
                                               const float* __restrict__ o1,
                                               const float* __restrict__ gw0,
                                               float* __restrict__ y0,
                                               float* __restrict__ bw)
{
    __shared__ __align__(16) unsigned short hb[2][2048];
    __shared__ __align__(16) float As[64][36];
    __shared__ __align__(16) float Ws[64][36];
    __shared__ float u2s[512];
    __shared__ float reds[512];
    __shared__ float lds_pad[12832];   // pushes LDS > 80 KB -> 1 block/CU

    const int bid = blockIdx.x;
    if (bid == 0x7fffffff) lds_pad[threadIdx.x] = 1.f;   // opaque keep-alive

    if (bid < 32) {
        __builtin_amdgcn_s_setprio(1);
        float* outp = o2;
        GRU_PROLOGUE(bid, whi, bhh, xw)
#pragma unroll 1
        for (int st = 0; st < 128; st += 2) {
            GRU_BODY(st,     0, xAr, xAz, xAn)
            GRU_BODY(st + 1, 1, xBr, xBz, xBn)
        }
        __builtin_amdgcn_s_setprio(0);
    } else if (bid < 288) {
        int g = bid - 32;
        gate_gemm_body(o1, gw0, y0, g & 3, (g >> 2) & 1, g >> 3, As, Ws);
    } else {
        int s = bid - 288;
        pair_stats_body(o1, s, &bw[s], u2s, reds);
    }
}

// ---------------- FAT2: gate_gemm1 (0..255) || pair_stats l1 (256..383) || fc (384..389) || prep (390..645) ----------------
__global__ __launch_bounds__(512, 1) void fat2(const float* __restrict__ o2,
                                               const float* __restrict__ gw1,
                                               float* __restrict__ y1,
                                               float* __restrict__ bw,
                                               const float* __restrict__ fcw,
                                               const float* __restrict__ fcb,
                                               float* __restrict__ outp,
                                               const float* __restrict__ o1,
                                               unsigned short* __restrict__ chi,
                                               unsigned short* __restrict__ clo,
                                               float* __restrict__ norms)
{
    __shared__ __align__(16) float As[64][36];
    __shared__ __align__(16) float Ws[64][36];
    __shared__ float u2s[512];
    __shared__ float reds[512];

    const int bid = blockIdx.x;
    if (bid < 256) {
        gate_gemm_body(o2, gw1, y1, bid & 3, (bid >> 2) & 1, bid >> 3, As, Ws);
    } else if (bid < 384) {
        int s = bid - 256;
        pair_stats_body(o2, s, &bw[128 + s], u2s, reds);
    } else if (bid < 390) {
        fc_body(bid - 384, o2, fcw, fcb, outp);
    } else {
        int idx = bid - 390;
        int s = idx & 127, l = idx >> 7;
        prep_body(l ? o2 : o1, s, l, chi, clo, norms);
    }
}

// ---------------- mmd tail: 2560 mmd + gate_reduce x2 ----------------
__global__ __launch_bounds__(256) void mmd_tail(const unsigned short* __restrict__ chi,
                                                const unsigned short* __restrict__ clo,
                                                const float* __restrict__ norms,
                                                const float* __restrict__ bw,
                                                float* __restrict__ mmdv,
                                                const float* __restrict__ y0, const float* __restrict__ y1,
                                                const float* __restrict__ g0, const float* __restrict__ b0,
                                                const float* __restrict__ g1, const float* __restrict__ b1,
                                                float* __restrict__ wts_ws, float* __restrict__ wts_out)
{
    __shared__ float rbuf[4];
    __shared__ float red[128];
    const int lin = blockIdx.x;
    if (lin < 2560) {
        const int v = (lin & 7) * 320 + (lin >> 3);
        mmd_body(chi, clo, norms, bw, mmdv, v / 10, v % 10, rbuf);
    } else {
        int which = lin - 2560;
        gate_reduce_body(which ? y1 : y0, which ? g1 : g0, which ? b1 : b0,
                         wts_ws + which * 128, wts_out + which * 128, red);
    }
}

// ---------------- final loss ----------------
__global__ void final_loss(const float* __restrict__ wts,
                           const float* __restrict__ mmdv,
                           float* __restrict__ out)
{
    const int t = threadIdx.x;
    float v = wts[t] * mmdv[t];
    __shared__ float red[256];
    red[t] = v;
    __syncthreads();
    for (int st = 128; st > 0; st >>= 1) {
        if (t < st) red[t] += red[t + st];
        __syncthreads();
    }
    if (t == 0) out[0] = red[0] * (1.f / 65536.f);
}

// ---------------- launch ----------------
extern "C" void kernel_launch(void* const* d_in, const int* in_sizes, int n_in,
                              void* d_out, int out_size, void* d_ws, size_t ws_size,
                              hipStream_t stream)
{
    (void)in_sizes; (void)n_in; (void)out_size; (void)ws_size;
    const float* x    = (const float*)d_in[0];
    const float* wih0 = (const float*)d_in[1];
    const float* whh0 = (const float*)d_in[2];
    const float* bih0 = (const float*)d_in[3];
    const float* bhh0 = (const float*)d_in[4];
    const float* wih1 = (const float*)d_in[5];
    const float* whh1 = (const float*)d_in[6];
    const float* bih1 = (const float*)d_in[7];
    const float* bhh1 = (const float*)d_in[8];
    const float* gw0  = (const float*)d_in[9];
    const float* bg0  = (const float*)d_in[11];
    const float* bb0  = (const float*)d_in[12];
    const float* gw1  = (const float*)d_in[13];
    const float* bg1  = (const float*)d_in[15];
    const float* bb1  = (const float*)d_in[16];
    const float* fcw  = (const float*)d_in[17];
    const float* fcb  = (const float*)d_in[18];

    float* out = (float*)d_out;
    char*  ws  = (char*)d_ws;
    float* xw   = (float*)(ws + XW_OFF);
    float* o1   = (float*)(ws + O1_OFF);
    float* o2   = (float*)(ws + O2_OFF);
    float* y0   = (float*)(ws + Y0_OFF);
    float* y1   = (float*)(ws + Y1_OFF);
    float* mmdv = (float*)(ws + MMD_OFF);
    float* wts  = (float*)(ws + WTS_OFF);
    float* bwv  = (float*)(ws + BW_OFF);
    float* nrm  = (float*)(ws + NRM_OFF);
    unsigned short* chi  = (unsigned short*)(ws + CHI_OFF);
    unsigned short* clo  = (unsigned short*)(ws + CLO_OFF);
    unsigned short* whi0 = (unsigned short*)(ws + WBF_OFF);
    unsigned short* wlo0 = whi0 + 49152;
    unsigned short* whi1 = wlo0 + 49152;
    unsigned short* wlo1 = whi1 + 49152;
    unsigned short* hhi0 = wlo1 + 49152;
    unsigned short* hlo0 = hhi0 + 49152;
    unsigned short* hhi1 = hlo0 + 49152;
    unsigned short* hlo1 = hhi1 + 49152;

    hipMemsetAsync(y0, 0, (256 * 128 * 2 + 256) * sizeof(float), stream);

    cvt_w4<<<dim3(48, 4), 256, 0, stream>>>(wih0, wih1, whh0, whh1,
                                            whi0, wlo0, whi1, wlo1,
                                            hhi0, hlo0, hhi1, hlo1);

    gemm_f32a<<<dim3(512, 3), 256, 0, stream>>>(x, whi0, wlo0, bih0, xw);
    gru_mfma<<<32, 512, 0, stream>>>(xw, hhi0, bhh0, o1);
    gemm_f32a<<<dim3(512, 3), 256, 0, stream>>>(o1, whi1, wlo1, bih1, xw);

    fat1<<<416, 512, 0, stream>>>(xw, hhi1, bhh1, o2, o1, gw0, y0, bwv);
    fat2<<<646, 512, 0, stream>>>(o2, gw1, y1, bwv, fcw, fcb, out, o1, chi, clo, nrm);

    mmd_tail<<<2562, 256, 0, stream>>>(chi, clo, nrm, bwv, mmdv,
                                       y0, y1, bg0, bb0, bg1, bb1, wts, out + 3073);

    final_loss<<<1, 256, 0, stream>>>(wts, mmdv, out + 3072);
}

// Round 27
// 573.420 us; speedup vs baseline: 1.0601x; 1.0601x over previous
//
#include <hip/hip_runtime.h>
#include <math.h>

typedef __attribute__((ext_vector_type(8))) short bf16x8;   // 8 bf16 (4 VGPRs)
typedef __attribute__((ext_vector_type(4))) float f32x4;

// ---------------- workspace layout (bytes) ----------------
constexpr size_t XW_OFF  = 0;                                   // 96 MB (gemm out; read by gru; dead after gru2)
constexpr size_t O1_OFF  = XW_OFF + 65536ull * 384 * 4;
constexpr size_t O2_OFF  = O1_OFF + 512ull * 128 * 128 * 4;
constexpr size_t Y0_OFF  = O2_OFF + 512ull * 128 * 128 * 4;
constexpr size_t Y1_OFF  = Y0_OFF + 256ull * 128 * 4;
constexpr size_t MMD_OFF = Y1_OFF + 256ull * 128 * 4;
constexpr size_t WTS_OFF = MMD_OFF + 256 * 4;
constexpr size_t BW_OFF  = WTS_OFF + 256 * 4;
constexpr size_t WBF_OFF = BW_OFF + 4096;                       // 8 bf16 weight slots = 768 KB
// aliases inside dead xw region (valid after gru2; prep runs in fat2):
constexpr size_t NRM_OFF = XW_OFF;
constexpr size_t CHI_OFF = XW_OFF + (1ull << 20);
constexpr size_t CLO_OFF = CHI_OFF + 36ull * 1024 * 1024;

static __device__ __forceinline__ unsigned short f2bf(float x) {
    unsigned u = __float_as_uint(x);
    unsigned r = (u + 0x7FFFu + ((u >> 16) & 1u)) >> 16;
    return (unsigned short)r;
}
static __device__ __forceinline__ float bf2f(unsigned short b) {
    return __uint_as_float((unsigned)b << 16);
}
static __device__ __forceinline__ void cvt8(const float* __restrict__ p,
                                            bf16x8* hi, bf16x8* lo) {
    float4 v0 = *(const float4*)p;
    float4 v1 = *(const float4*)(p + 4);
    union { unsigned short us[8]; bf16x8 v; } H, L;
    float f[8] = {v0.x, v0.y, v0.z, v0.w, v1.x, v1.y, v1.z, v1.w};
#pragma unroll
    for (int i = 0; i < 8; ++i) {
        H.us[i] = f2bf(f[i]);
        L.us[i] = f2bf(f[i] - bf2f(H.us[i]));
    }
    *hi = H.v; *lo = L.v;
}

// ---------------- cvt_w4 ----------------
__global__ __launch_bounds__(256) void cvt_w4(const float* __restrict__ W0, const float* __restrict__ W1,
                                              const float* __restrict__ W2, const float* __restrict__ W3,
                                              unsigned short* __restrict__ H0, unsigned short* __restrict__ L0,
                                              unsigned short* __restrict__ H1, unsigned short* __restrict__ L1,
                                              unsigned short* __restrict__ H2, unsigned short* __restrict__ L2,
                                              unsigned short* __restrict__ H3, unsigned short* __restrict__ L3)
{
    const int which = blockIdx.y;
    const float* W = (which == 0) ? W0 : (which == 1) ? W1 : (which == 2) ? W2 : W3;
    unsigned short* whi = (which == 0) ? H0 : (which == 1) ? H1 : (which == 2) ? H2 : H3;
    unsigned short* wlo = (which == 0) ? L0 : (which == 1) ? L1 : (which == 2) ? L2 : L3;
    int f = blockIdx.x * 256 + threadIdx.x;
    if (f >= 12288) return;
    float4 v = ((const float4*)W)[f];
    ushort4 uh, ul;
    uh.x = f2bf(v.x); ul.x = f2bf(v.x - bf2f(uh.x));
    uh.y = f2bf(v.y); ul.y = f2bf(v.y - bf2f(uh.y));
    uh.z = f2bf(v.z); ul.z = f2bf(v.z - bf2f(uh.z));
    uh.w = f2bf(v.w); ul.w = f2bf(v.w - bf2f(uh.w));
    *(ushort4*)(whi + 4 * f) = uh;
    *(ushort4*)(wlo + 4 * f) = ul;
}

// ---------------- gemm: C[M][384] = A_f32 @ W^T + bias ----------------
__global__ __launch_bounds__(256) void gemm_f32a(const float* __restrict__ A,
                                                 const unsigned short* __restrict__ whi,
                                                 const unsigned short* __restrict__ wlo,
                                                 const float* __restrict__ bias,
                                                 float* __restrict__ C)
{
    const int m0 = blockIdx.x * 128;
    const int n0 = blockIdx.y * 128;
    const int tid  = threadIdx.x;
    const int lane = tid & 63;
    const int wave = tid >> 6;
    const int wm = wave >> 1, wn = wave & 1;
    const int r16 = lane & 15;
    const int kq  = lane >> 4;

    const int arow = m0 + wm * 64 + r16;
    const int brow = n0 + wn * 64 + r16;

    f32x4 acc[4][4];
#pragma unroll
    for (int mf = 0; mf < 4; ++mf)
#pragma unroll
        for (int nf = 0; nf < 4; ++nf) acc[mf][nf] = (f32x4){0.f, 0.f, 0.f, 0.f};

#pragma unroll 1
    for (int kc = 0; kc < 128; kc += 32) {
        const int koff = kc + 8 * kq;
        bf16x8 ah[4], al[4], bh[4], bl[4];
#pragma unroll
        for (int mf = 0; mf < 4; ++mf)
            cvt8(A + (size_t)(arow + mf * 16) * 128 + koff, &ah[mf], &al[mf]);
#pragma unroll
        for (int nf = 0; nf < 4; ++nf) {
            size_t off = (size_t)(brow + nf * 16) * 128 + koff;
            bh[nf] = *(const bf16x8*)(whi + off);
            bl[nf] = *(const bf16x8*)(wlo + off);
        }
#pragma unroll
        for (int mf = 0; mf < 4; ++mf)
#pragma unroll
            for (int nf = 0; nf < 4; ++nf) {
                acc[mf][nf] = __builtin_amdgcn_mfma_f32_16x16x32_bf16(ah[mf], bh[nf], acc[mf][nf], 0, 0, 0);
                acc[mf][nf] = __builtin_amdgcn_mfma_f32_16x16x32_bf16(ah[mf], bl[nf], acc[mf][nf], 0, 0, 0);
                acc[mf][nf] = __builtin_amdgcn_mfma_f32_16x16x32_bf16(al[mf], bh[nf], acc[mf][nf], 0, 0, 0);
            }
    }

    float nb[4];
#pragma unroll
    for (int nf = 0; nf < 4; ++nf) nb[nf] = bias[n0 + wn * 64 + nf * 16 + r16];

#pragma unroll
    for (int mf = 0; mf < 4; ++mf)
#pragma unroll
        for (int nf = 0; nf < 4; ++nf)
#pragma unroll
            for (int r = 0; r < 4; ++r) {
                int row = m0 + wm * 64 + mf * 16 + kq * 4 + r;
                int col = n0 + wn * 64 + nf * 16 + r16;
                C[(size_t)row * 384 + col] = acc[mf][nf][r] + nb[nf];
            }
}

// ---------------- GRU macros: single-bf16 h AND single-bf16 whh ----------------
#define GRU_BODY(STCUR, CUR, XR, XZ, XN)                                              \
    {                                                                                 \
        bf16x8 Bh[4];                                                                 \
        _Pragma("unroll")                                                             \
        for (int c = 0; c < 4; ++c) {                                                 \
            int rslot = (b * 128 + 32 * c + 8 * kq) ^ ((b & 7) << 3);                 \
            Bh[c] = *(const bf16x8*)&hb[CUR][rslot];                                  \
        }                                                                             \
        f32x4 acc[3];                                                                 \
        _Pragma("unroll")                                                             \
        for (int g = 0; g < 3; ++g) acc[g] = (f32x4){0.f, 0.f, 0.f, 0.f};             \
        _Pragma("unroll")                                                             \
        for (int c = 0; c < 4; ++c)                                                   \
            _Pragma("unroll")                                                         \
            for (int g = 0; g < 3; ++g)                                               \
                acc[g] = __builtin_amdgcn_mfma_f32_16x16x32_bf16(Ah[g][c], Bh[c], acc[g], 0, 0, 0); \
        f32x4 hnew;                                                                   \
        ushort4 nhi;                                                                  \
        _Pragma("unroll")                                                             \
        for (int r = 0; r < 4; ++r) {                                                 \
            float rr = 1.f / (1.f + __expf(-(XR[r] + acc[0][r] + bh[0][r])));         \
            float zz = 1.f / (1.f + __expf(-(XZ[r] + acc[1][r] + bh[1][r])));         \
            float xa = XN[r] + rr * (acc[2][r] + bh[2][r]);                           \
            float ex = __expf(-2.f * fabsf(xa));                                      \
            float th = (1.f - ex) / (1.f + ex);                                       \
            th = copysignf(th, xa);                                                   \
            hnew[r] = (1.f - zz) * th + zz * hold[r];                                 \
        }                                                                             \
        hold = hnew;                                                                  \
        nhi.x = f2bf(hnew[0]);                                                        \
        nhi.y = f2bf(hnew[1]);                                                        \
        nhi.z = f2bf(hnew[2]);                                                        \
        nhi.w = f2bf(hnew[3]);                                                        \
        *(ushort4*)&hb[(CUR) ^ 1][wslot] = nhi;                                       \
        *(f32x4*)(outp + ((size_t)B * 128 + (STCUR)) * 128 + u0) = hnew;              \
        {                                                                             \
            const int ld = ((STCUR) + 2 < 128) ? (STCUR) + 2 : 127;                   \
            XR = *(const f32x4*)(xb + ld * 384 + u0);                                 \
            XZ = *(const f32x4*)(xb + ld * 384 + 128 + u0);                           \
            XN = *(const f32x4*)(xb + ld * 384 + 256 + u0);                           \
        }                                                                             \
        asm volatile("s_waitcnt lgkmcnt(0)" ::: "memory");                            \
        __builtin_amdgcn_s_barrier();                                                 \
    }

#define GRU_PROLOGUE(BLK, WHI, BHH, XW)                                               \
    const int tid  = threadIdx.x;                                                     \
    const int w    = tid >> 6;                                                        \
    const int lane = tid & 63;                                                        \
    const int b    = lane & 15;                                                       \
    const int kq   = lane >> 4;                                                       \
    const int u0   = 16 * w + 4 * kq;                                                 \
    const int B    = (BLK) * 16 + b;                                                  \
    bf16x8 Ah[3][4];                                                                  \
    _Pragma("unroll")                                                                 \
    for (int g = 0; g < 3; ++g)                                                       \
        _Pragma("unroll")                                                             \
        for (int c = 0; c < 4; ++c) {                                                 \
            size_t off = (size_t)(128 * g + 16 * w + b) * 128 + 32 * c + 8 * kq;      \
            Ah[g][c] = *(const bf16x8*)((WHI) + off);                                 \
        }                                                                             \
    f32x4 bh[3];                                                                      \
    _Pragma("unroll")                                                                 \
    for (int g = 0; g < 3; ++g) bh[g] = *(const f32x4*)((BHH) + 128 * g + u0);        \
    const int wslot = (b * 128 + u0) ^ ((b & 7) << 3);                                \
    *(ushort4*)&hb[0][wslot] = (ushort4){0, 0, 0, 0};                                 \
    __syncthreads();                                                                  \
    f32x4 hold = (f32x4){0.f, 0.f, 0.f, 0.f};                                         \
    const float* xb = (XW) + (size_t)B * 128 * 384;                                   \
    f32x4 xAr = *(const f32x4*)(xb + u0);                                             \
    f32x4 xAz = *(const f32x4*)(xb + 128 + u0);                                       \
    f32x4 xAn = *(const f32x4*)(xb + 256 + u0);                                       \
    f32x4 xBr = *(const f32x4*)(xb + 384 + u0);                                       \
    f32x4 xBz = *(const f32x4*)(xb + 384 + 128 + u0);                                 \
    f32x4 xBn = *(const f32x4*)(xb + 384 + 256 + u0);

// ---------------- GRU layer 1 ----------------
__global__ __launch_bounds__(512, 1) void gru_mfma(const float* __restrict__ xw,
                                                   const unsigned short* __restrict__ whi,
                                                   const float* __restrict__ bhh,
                                                   float* __restrict__ outp)
{
    __shared__ __align__(16) unsigned short hb[2][2048];
    GRU_PROLOGUE(blockIdx.x, whi, bhh, xw)
#pragma unroll 1
    for (int st = 0; st < 128; st += 2) {
        GRU_BODY(st,     0, xAr, xAz, xAn)
        GRU_BODY(st + 1, 1, xBr, xBz, xBn)
    }
}

// ---------------- bodies ----------------
static __device__ __forceinline__ void gate_gemm_body(const float* __restrict__ o,
                                                      const float* __restrict__ gw,
                                                      float* __restrict__ y,
                                                      int gx, int gy, int gz,
                                                      float (*As)[36], float (*Ws)[36])
{
    const int tid = threadIdx.x;
    const int tx = tid & 15, ty = (tid >> 4) & 31;
    const int m0 = gx * 64, n0 = gy * 64;
    const int k0beg = gz * 1024;

    float acc[2][4];
#pragma unroll
    for (int i = 0; i < 2; ++i)
#pragma unroll
        for (int j = 0; j < 4; ++j) acc[i][j] = 0.f;

#pragma unroll 1
    for (int kc = k0beg; kc < k0beg + 1024; kc += 32) {
        {
            int row = tid >> 3;
            int c4  = (tid & 7) * 4;
            int kap = kc + c4;
            int s = kap >> 8, half = (kap >> 7) & 1, h = kap & 127;
            float4 va = *(const float4*)(o + ((size_t)(m0 + row + 256 * half) * 128 + s) * 128 + h);
            *(float4*)&As[row][c4] = va;
            float4 vw = *(const float4*)(gw + (size_t)(n0 + row) * 32768 + kap);
            *(float4*)&Ws[row][c4] = vw;
        }
        __syncthreads();
#pragma unroll 1
        for (int k0 = 0; k0 < 32; k0 += 4) {
            float4 a4[2], w4[4];
#pragma unroll
            for (int i = 0; i < 2; ++i) a4[i] = *(float4*)&As[ty + 32 * i][k0];
#pragma unroll
            for (int j = 0; j < 4; ++j) w4[j] = *(float4*)&Ws[tx + 16 * j][k0];
#pragma unroll
            for (int i = 0; i < 2; ++i)
#pragma unroll
                for (int j = 0; j < 4; ++j) {
                    acc[i][j] += a4[i].x * w4[j].x + a4[i].y * w4[j].y +
                                 a4[i].z * w4[j].z + a4[i].w * w4[j].w;
                }
        }
        __syncthreads();
    }
#pragma unroll
    for (int i = 0; i < 2; ++i)
#pragma unroll
        for (int j = 0; j < 4; ++j) {
            int r = m0 + ty + 32 * i, c = n0 + tx + 16 * j;
            atomicAdd(&y[r * 128 + c], acc[i][j]);
        }
}

static __device__ __forceinline__ void pair_stats_body(const float* __restrict__ o, int s,
                                                       float* __restrict__ bwp,
                                                       float* u2, float* red)
{
    const int tid = threadIdx.x;
    const int h = tid & 127, q = tid >> 7;

    float acc_u = 0.f, acc_sq = 0.f;
    for (int r = 0; r < 128; ++r) {
        int i = q * 128 + r;
        float v = o[((size_t)i * 128 + s) * 128 + h];
        acc_u += v; acc_sq += v * v;
    }
    u2[tid] = acc_u;
    red[tid] = acc_sq;
    __syncthreads();
    for (int st = 256; st > 0; st >>= 1) {
        if (tid < st) red[tid] += red[tid + st];
        __syncthreads();
    }
    float S1 = red[0];
    __syncthreads();
    float uu = 0.f;
    if (tid < 128) {
        float t = u2[tid] + u2[tid + 128] + u2[tid + 256] + u2[tid + 384];
        uu = t * t;
    }
    red[tid] = (tid < 128) ? uu : 0.f;
    __syncthreads();
    for (int st = 64; st > 0; st >>= 1) {
        if (tid < st) red[tid] += red[tid + st];
        __syncthreads();
    }
    if (tid == 0) {
        float S2 = red[0];
        float d2s = 1024.f * S1 - 2.f * S2;
        *bwp = d2s / (512.f * 512.f - 512.f) * 0.25f;
    }
}

static __device__ __forceinline__ void prep_body(const float* __restrict__ o, int s, int l,
                                                 unsigned short* __restrict__ chi,
                                                 unsigned short* __restrict__ clo,
                                                 float* __restrict__ norms)
{
    const int t = threadIdx.x;
    const int h4 = (t & 31) * 4;
    const size_t pb = ((size_t)l * 128 + s) * 512 * 128;
    float* np_ = norms + ((size_t)l * 128 + s) * 512;
#pragma unroll 1
    for (int i = t >> 5; i < 512; i += 16) {
        float4 v = *(const float4*)(o + ((size_t)i * 128 + s) * 128 + h4);
        ushort4 uh, ul;
        uh.x = f2bf(v.x); ul.x = f2bf(v.x - bf2f(uh.x));
        uh.y = f2bf(v.y); ul.y = f2bf(v.y - bf2f(uh.y));
        uh.z = f2bf(v.z); ul.z = f2bf(v.z - bf2f(uh.z));
        uh.w = f2bf(v.w); ul.w = f2bf(v.w - bf2f(uh.w));
        *(ushort4*)(chi + pb + (size_t)i * 128 + h4) = uh;
        *(ushort4*)(clo + pb + (size_t)i * 128 + h4) = ul;
        float sq = v.x * v.x + v.y * v.y + v.z * v.z + v.w * v.w;
        sq += __shfl_xor(sq, 1);
        sq += __shfl_xor(sq, 2);
        sq += __shfl_xor(sq, 4);
        sq += __shfl_xor(sq, 8);
        sq += __shfl_xor(sq, 16);
        if ((t & 31) == 0) np_[i] = sq;
    }
}

static __device__ __forceinline__ void fc_body(int bid0, const float* __restrict__ o2,
                                               const float* __restrict__ fcw,
                                               const float* __restrict__ fcb,
                                               float* __restrict__ outp)
{
    int gid = bid0 * 512 + threadIdx.x;
    if (gid < 3072) {
        int b = gid / 6, oo = gid - b * 6;
        const float* xr = o2 + ((size_t)b * 128 + 127) * 128;
        const float* wr = fcw + oo * 128;
        float acc = fcb[oo];
#pragma unroll 16
        for (int k = 0; k < 128; ++k) acc += xr[k] * wr[k];
        outp[gid] = acc;
    }
}

static __device__ __forceinline__ void mmd_body(const unsigned short* __restrict__ chi,
                                                const unsigned short* __restrict__ clo,
                                                const float* __restrict__ norms,
                                                const float* __restrict__ bw,
                                                float* __restrict__ mmdv,
                                                int p, int tp, float* rbuf)
{
    int ti, tj;
    if (tp < 4)      { ti = 0; tj = tp; }
    else if (tp < 7) { ti = 1; tj = tp - 3; }
    else if (tp < 9) { ti = 2; tj = tp - 5; }
    else             { ti = 3; tj = 3; }
    const float sgn  = ((ti < 2) == (tj < 2)) ? 1.f : -1.f;
    const float coef = sgn * ((ti == tj) ? 1.f : 2.f);

    const int tid  = threadIdx.x;
    const int lane = tid & 63;
    const int wave = tid >> 6;
    const int wm = wave >> 1, wn = wave & 1;
    const int r16 = lane & 15;
    const int kq  = lane >> 4;

    const size_t pbase = (size_t)p * 512 * 128;
    const int arow = ti * 128 + wm * 64 + r16;
    const int brow = tj * 128 + wn * 64 + r16;

    f32x4 acc[4][4];
#pragma unroll
    for (int mf = 0; mf < 4; ++mf)
#pragma unroll
        for (int nf = 0; nf < 4; ++nf) acc[mf][nf] = (f32x4){0.f, 0.f, 0.f, 0.f};

#pragma unroll 1
    for (int kc = 0; kc < 128; kc += 32) {
        const size_t koff = (size_t)kc + 8 * kq;
        bf16x8 ah[4], al[4], bh[4], bl[4];
#pragma unroll
        for (int mf = 0; mf < 4; ++mf) {
            size_t off = pbase + (size_t)(arow + mf * 16) * 128 + koff;
            ah[mf] = *(const bf16x8*)(chi + off);
            al[mf] = *(const bf16x8*)(clo + off);
        }
#pragma unroll
        for (int nf = 0; nf < 4; ++nf) {
            size_t off = pbase + (size_t)(brow + nf * 16) * 128 + koff;
            bh[nf] = *(const bf16x8*)(chi + off);
            bl[nf] = *(const bf16x8*)(clo + off);
        }
#pragma unroll
        for (int mf = 0; mf < 4; ++mf)
#pragma unroll
            for (int nf = 0; nf < 4; ++nf) {
                acc[mf][nf] = __builtin_amdgcn_mfma_f32_16x16x32_bf16(ah[mf], bh[nf], acc[mf][nf], 0, 0, 0);
                acc[mf][nf] = __builtin_amdgcn_mfma_f32_16x16x32_bf16(ah[mf], bl[nf], acc[mf][nf], 0, 0, 0);
                acc[mf][nf] = __builtin_amdgcn_mfma_f32_16x16x32_bf16(al[mf], bh[nf], acc[mf][nf], 0, 0, 0);
            }
    }

    const float* np_ = norms + (size_t)p * 512;
    float na[4][4], nb[4];
#pragma unroll
    for (int mf = 0; mf < 4; ++mf)
#pragma unroll
        for (int r = 0; r < 4; ++r)
            na[mf][r] = np_[ti * 128 + wm * 64 + mf * 16 + (lane >> 4) * 4 + r];
#pragma unroll
    for (int nf = 0; nf < 4; ++nf)
        nb[nf] = np_[tj * 128 + wn * 64 + nf * 16 + (lane & 15)];

    const float bwv = bw[p];
    const float c4 = -1.f / (bwv * 16.f);
    float tot = 0.f;
#pragma unroll
    for (int mf = 0; mf < 4; ++mf)
#pragma unroll
        for (int nf = 0; nf < 4; ++nf)
#pragma unroll
            for (int r = 0; r < 4; ++r) {
                float d2 = na[mf][r] + nb[nf] - 2.f * acc[mf][nf][r];
                float e4 = __expf(c4 * d2);
                float e3 = e4 * e4;
                float e2 = e3 * e3;
                float e1 = e2 * e2;
                float e0 = e1 * e1;
                tot += ((e0 + e1) + (e2 + e3)) + e4;
            }
    tot *= coef;

    for (int off = 32; off > 0; off >>= 1) tot += __shfl_down(tot, off);
    if ((tid & 63) == 0) rbuf[tid >> 6] = tot;
    __syncthreads();
    if (tid == 0) atomicAdd(&mmdv[p], rbuf[0] + rbuf[1] + rbuf[2] + rbuf[3]);
}

static __device__ __forceinline__ void gate_reduce_body(const float* __restrict__ y,
                                                        const float* __restrict__ gamma,
                                                        const float* __restrict__ beta,
                                                        float* __restrict__ ws_p,
                                                        float* __restrict__ out_p,
                                                        float* red)
{
    const int o = threadIdx.x;
    const bool act = (o < 128);
    float wo = 0.f;
    if (act) {
        float sum = 0.f, sumsq = 0.f;
        for (int b = 0; b < 256; ++b) {
            float v = y[b * 128 + o];
            sum += v; sumsq += v * v;
        }
        float m = sum * (1.f / 256.f);
        float var = sumsq * (1.f / 256.f) - m * m;
        float inv = rsqrtf(var + 1e-5f);
        float g = gamma[o], be = beta[o];
        float sw = 0.f;
        for (int b = 0; b < 256; ++b) {
            float v = y[b * 128 + o];
            float t = g * (v - m) * inv + be;
            sw += 1.f / (1.f + __expf(-t));
        }
        wo = sw * (1.f / 256.f);
        red[o] = wo;
    }
    __syncthreads();
    for (int st = 64; st > 0; st >>= 1) {
        if (act && o < st) red[o] = fmaxf(red[o], red[o + st]);
        __syncthreads();
    }
    float mx = red[0];
    __syncthreads();
    float e = act ? __expf(wo - mx) : 0.f;
    if (act) red[o] = e;
    __syncthreads();
    for (int st = 64; st > 0; st >>= 1) {
        if (act && o < st) red[o] += red[o + st];
        __syncthreads();
    }
    if (act) {
        float r = e / red[0];
        ws_p[o] = r;
        out_p[o] = r;
    }
}

// ---------------- FAT1: gru2 (0..31, prio 1) || gate_gemm0 (32..287) || pair_stats l0 (288..415) ----------------
// Launched with 56 KB dynamic LDS -> total 88 KB/block -> 1 block/CU, so no
// gate/pair block co-schedules on a gru CU (R24 co-residency diagnosis; the
// R26 static pad was DCE'd -- dynamic LDS cannot be).
__global__ __launch_bounds__(512, 1) void fat1(const float* __restrict__ xw,
                                               const unsigned short* __restrict__ whi,
                                               const float* __restrict__ bhh,
                                               float* __restrict__ o2,
                                               const float* __restrict__ o1,
                                               const float* __restrict__ gw0,
                                               float* __restrict__ y0,
                                               float* __restrict__ bw)
{
    __shared__ __align__(16) unsigned short hb[2][2048];
    __shared__ __align__(16) float As[64][36];
    __shared__ __align__(16) float Ws[64][36];
    __shared__ float u2s[512];
    __shared__ float reds[512];

    const int bid = blockIdx.x;
    if (bid < 32) {
        __builtin_amdgcn_s_setprio(1);
        float* outp = o2;
        GRU_PROLOGUE(bid, whi, bhh, xw)
#pragma unroll 1
        for (int st = 0; st < 128; st += 2) {
            GRU_BODY(st,     0, xAr, xAz, xAn)
            GRU_BODY(st + 1, 1, xBr, xBz, xBn)
        }
        __builtin_amdgcn_s_setprio(0);
    } else if (bid < 288) {
        int g = bid - 32;
        gate_gemm_body(o1, gw0, y0, g & 3, (g >> 2) & 1, g >> 3, As, Ws);
    } else {
        int s = bid - 288;
        pair_stats_body(o1, s, &bw[s], u2s, reds);
    }
}

// ---------------- FAT2: gate_gemm1 (0..255) || pair_stats l1 (256..383) || fc (384..389) || prep (390..645) ----------------
__global__ __launch_bounds__(512, 1) void fat2(const float* __restrict__ o2,
                                               const float* __restrict__ gw1,
                                               float* __restrict__ y1,
                                               float* __restrict__ bw,
                                               const float* __restrict__ fcw,
                                               const float* __restrict__ fcb,
                                               float* __restrict__ outp,
                                               const float* __restrict__ o1,
                                               unsigned short* __restrict__ chi,
                                               unsigned short* __restrict__ clo,
                                               float* __restrict__ norms)
{
    __shared__ __align__(16) float As[64][36];
    __shared__ __align__(16) float Ws[64][36];
    __shared__ float u2s[512];
    __shared__ float reds[512];

    const int bid = blockIdx.x;
    if (bid < 256) {
        gate_gemm_body(o2, gw1, y1, bid & 3, (bid >> 2) & 1, bid >> 3, As, Ws);
    } else if (bid < 384) {
        int s = bid - 256;
        pair_stats_body(o2, s, &bw[128 + s], u2s, reds);
    } else if (bid < 390) {
        fc_body(bid - 384, o2, fcw, fcb, outp);
    } else {
        int idx = bid - 390;
        int s = idx & 127, l = idx >> 7;
        prep_body(l ? o2 : o1, s, l, chi, clo, norms);
    }
}

// ---------------- mmd tail: 2560 mmd + gate_reduce x2 ----------------
__global__ __launch_bounds__(256) void mmd_tail(const unsigned short* __restrict__ chi,
                                                const unsigned short* __restrict__ clo,
                                                const float* __restrict__ norms,
                                                const float* __restrict__ bw,
                                                float* __restrict__ mmdv,
                                                const float* __restrict__ y0, const float* __restrict__ y1,
                                                const float* __restrict__ g0, const float* __restrict__ b0,
                                                const float* __restrict__ g1, const float* __restrict__ b1,
                                                float* __restrict__ wts_ws, float* __restrict__ wts_out)
{
    __shared__ float rbuf[4];
    __shared__ float red[128];
    const int lin = blockIdx.x;
    if (lin < 2560) {
        const int v = (lin & 7) * 320 + (lin >> 3);
        mmd_body(chi, clo, norms, bw, mmdv, v / 10, v % 10, rbuf);
    } else {
        int which = lin - 2560;
        gate_reduce_body(which ? y1 : y0, which ? g1 : g0, which ? b1 : b0,
                         wts_ws + which * 128, wts_out + which * 128, red);
    }
}

// ---------------- final loss ----------------
__global__ void final_loss(const float* __restrict__ wts,
                           const float* __restrict__ mmdv,
                           float* __restrict__ out)
{
    const int t = threadIdx.x;
    float v = wts[t] * mmdv[t];
    __shared__ float red[256];
    red[t] = v;
    __syncthreads();
    for (int st = 128; st > 0; st >>= 1) {
        if (t < st) red[t] += red[t + st];
        __syncthreads();
    }
    if (t == 0) out[0] = red[0] * (1.f / 65536.f);
}

// ---------------- launch ----------------
extern "C" void kernel_launch(void* const* d_in, const int* in_sizes, int n_in,
                              void* d_out, int out_size, void* d_ws, size_t ws_size,
                              hipStream_t stream)
{
    (void)in_sizes; (void)n_in; (void)out_size; (void)ws_size;
    const float* x    = (const float*)d_in[0];
    const float* wih0 = (const float*)d_in[1];
    const float* whh0 = (const float*)d_in[2];
    const float* bih0 = (const float*)d_in[3];
    const float* bhh0 = (const float*)d_in[4];
    const float* wih1 = (const float*)d_in[5];
    const float* whh1 = (const float*)d_in[6];
    const float* bih1 = (const float*)d_in[7];
    const float* bhh1 = (const float*)d_in[8];
    const float* gw0  = (const float*)d_in[9];
    const float* bg0  = (const float*)d_in[11];
    const float* bb0  = (const float*)d_in[12];
    const float* gw1  = (const float*)d_in[13];
    const float* bg1  = (const float*)d_in[15];
    const float* bb1  = (const float*)d_in[16];
    const float* fcw  = (const float*)d_in[17];
    const float* fcb  = (const float*)d_in[18];

    float* out = (float*)d_out;
    char*  ws  = (char*)d_ws;
    float* xw   = (float*)(ws + XW_OFF);
    float* o1   = (float*)(ws + O1_OFF);
    float* o2   = (float*)(ws + O2_OFF);
    float* y0   = (float*)(ws + Y0_OFF);
    float* y1   = (float*)(ws + Y1_OFF);
    float* mmdv = (float*)(ws + MMD_OFF);
    float* wts  = (float*)(ws + WTS_OFF);
    float* bwv  = (float*)(ws + BW_OFF);
    float* nrm  = (float*)(ws + NRM_OFF);
    unsigned short* chi  = (unsigned short*)(ws + CHI_OFF);
    unsigned short* clo  = (unsigned short*)(ws + CLO_OFF);
    unsigned short* whi0 = (unsigned short*)(ws + WBF_OFF);
    unsigned short* wlo0 = whi0 + 49152;
    unsigned short* whi1 = wlo0 + 49152;
    unsigned short* wlo1 = whi1 + 49152;
    unsigned short* hhi0 = wlo1 + 49152;
    unsigned short* hlo0 = hhi0 + 49152;
    unsigned short* hhi1 = hlo0 + 49152;
    unsigned short* hlo1 = hhi1 + 49152;

    hipMemsetAsync(y0, 0, (256 * 128 * 2 + 256) * sizeof(float), stream);

    cvt_w4<<<dim3(48, 4), 256, 0, stream>>>(wih0, wih1, whh0, whh1,
                                            whi0, wlo0, whi1, wlo1,
                                            hhi0, hlo0, hhi1, hlo1);

    gemm_f32a<<<dim3(512, 3), 256, 0, stream>>>(x, whi0, wlo0, bih0, xw);
    gru_mfma<<<32, 512, 0, stream>>>(xw, hhi0, bhh0, o1);
    gemm_f32a<<<dim3(512, 3), 256, 0, stream>>>(o1, whi1, wlo1, bih1, xw);

    // 56 KB dynamic LDS: total 88 KB/block -> hard 1 block/CU (cannot be DCE'd)
    fat1<<<416, 512, 56 * 1024, stream>>>(xw, hhi1, bhh1, o2, o1, gw0, y0, bwv);
    fat2<<<646, 512, 0, stream>>>(o2, gw1, y1, bwv, fcw, fcb, out, o1, chi, clo, nrm);

    mmd_tail<<<2562, 256, 0, stream>>>(chi, clo, nrm, bwv, mmdv,
                                       y0, y1, bg0, bb0, bg1, bb1, wts, out + 3073);

    final_loss<<<1, 256, 0, stream>>>(wts, mmdv, out + 3072);
}

// Round 28
// 542.034 us; speedup vs baseline: 1.1215x; 1.0579x over previous
//
#include <hip/hip_runtime.h>
#include <math.h>

typedef __attribute__((ext_vector_type(8))) short bf16x8;   // 8 bf16 (4 VGPRs)
typedef __attribute__((ext_vector_type(4))) float f32x4;

// ---------------- workspace layout (bytes) ----------------
constexpr size_t XW_OFF  = 0;                                   // 96 MB (gemm out; read by gru; dead after gru2)
constexpr size_t O1_OFF  = XW_OFF + 65536ull * 384 * 4;
constexpr size_t O2_OFF  = O1_OFF + 512ull * 128 * 128 * 4;
constexpr size_t Y0_OFF  = O2_OFF + 512ull * 128 * 128 * 4;
constexpr size_t Y1_OFF  = Y0_OFF + 256ull * 128 * 4;
constexpr size_t MMD_OFF = Y1_OFF + 256ull * 128 * 4;
constexpr size_t WTS_OFF = MMD_OFF + 256 * 4;
constexpr size_t BW_OFF  = WTS_OFF + 256 * 4;
constexpr size_t WBF_OFF = BW_OFF + 4096;                       // 8 bf16 weight slots = 768 KB
// aliases inside dead xw region (valid after gru2; prep runs in fat2):
constexpr size_t NRM_OFF = XW_OFF;
constexpr size_t CHI_OFF = XW_OFF + (1ull << 20);
constexpr size_t CLO_OFF = CHI_OFF + 36ull * 1024 * 1024;

static __device__ __forceinline__ unsigned short f2bf(float x) {
    unsigned u = __float_as_uint(x);
    unsigned r = (u + 0x7FFFu + ((u >> 16) & 1u)) >> 16;
    return (unsigned short)r;
}
static __device__ __forceinline__ float bf2f(unsigned short b) {
    return __uint_as_float((unsigned)b << 16);
}
static __device__ __forceinline__ void cvt8(const float* __restrict__ p,
                                            bf16x8* hi, bf16x8* lo) {
    float4 v0 = *(const float4*)p;
    float4 v1 = *(const float4*)(p + 4);
    union { unsigned short us[8]; bf16x8 v; } H, L;
    float f[8] = {v0.x, v0.y, v0.z, v0.w, v1.x, v1.y, v1.z, v1.w};
#pragma unroll
    for (int i = 0; i < 8; ++i) {
        H.us[i] = f2bf(f[i]);
        L.us[i] = f2bf(f[i] - bf2f(H.us[i]));
    }
    *hi = H.v; *lo = L.v;
}

// ---------------- cvt_w4 ----------------
__global__ __launch_bounds__(256) void cvt_w4(const float* __restrict__ W0, const float* __restrict__ W1,
                                              const float* __restrict__ W2, const float* __restrict__ W3,
                                              unsigned short* __restrict__ H0, unsigned short* __restrict__ L0,
                                              unsigned short* __restrict__ H1, unsigned short* __restrict__ L1,
                                              unsigned short* __restrict__ H2, unsigned short* __restrict__ L2,
                                              unsigned short* __restrict__ H3, unsigned short* __restrict__ L3)
{
    const int which = blockIdx.y;
    const float* W = (which == 0) ? W0 : (which == 1) ? W1 : (which == 2) ? W2 : W3;
    unsigned short* whi = (which == 0) ? H0 : (which == 1) ? H1 : (which == 2) ? H2 : H3;
    unsigned short* wlo = (which == 0) ? L0 : (which == 1) ? L1 : (which == 2) ? L2 : L3;
    int f = blockIdx.x * 256 + threadIdx.x;
    if (f >= 12288) return;
    float4 v = ((const float4*)W)[f];
    ushort4 uh, ul;
    uh.x = f2bf(v.x); ul.x = f2bf(v.x - bf2f(uh.x));
    uh.y = f2bf(v.y); ul.y = f2bf(v.y - bf2f(uh.y));
    uh.z = f2bf(v.z); ul.z = f2bf(v.z - bf2f(uh.z));
    uh.w = f2bf(v.w); ul.w = f2bf(v.w - bf2f(uh.w));
    *(ushort4*)(whi + 4 * f) = uh;
    *(ushort4*)(wlo + 4 * f) = ul;
}

// ---------------- gemm: C[M][384] = A_f32 @ W^T + bias ----------------
__global__ __launch_bounds__(256) void gemm_f32a(const float* __restrict__ A,
                                                 const unsigned short* __restrict__ whi,
                                                 const unsigned short* __restrict__ wlo,
                                                 const float* __restrict__ bias,
                                                 float* __restrict__ C)
{
    const int m0 = blockIdx.x * 128;
    const int n0 = blockIdx.y * 128;
    const int tid  = threadIdx.x;
    const int lane = tid & 63;
    const int wave = tid >> 6;
    const int wm = wave >> 1, wn = wave & 1;
    const int r16 = lane & 15;
    const int kq  = lane >> 4;

    const int arow = m0 + wm * 64 + r16;
    const int brow = n0 + wn * 64 + r16;

    f32x4 acc[4][4];
#pragma unroll
    for (int mf = 0; mf < 4; ++mf)
#pragma unroll
        for (int nf = 0; nf < 4; ++nf) acc[mf][nf] = (f32x4){0.f, 0.f, 0.f, 0.f};

#pragma unroll 1
    for (int kc = 0; kc < 128; kc += 32) {
        const int koff = kc + 8 * kq;
        bf16x8 ah[4], al[4], bh[4], bl[4];
#pragma unroll
        for (int mf = 0; mf < 4; ++mf)
            cvt8(A + (size_t)(arow + mf * 16) * 128 + koff, &ah[mf], &al[mf]);
#pragma unroll
        for (int nf = 0; nf < 4; ++nf) {
            size_t off = (size_t)(brow + nf * 16) * 128 + koff;
            bh[nf] = *(const bf16x8*)(whi + off);
            bl[nf] = *(const bf16x8*)(wlo + off);
        }
#pragma unroll
        for (int mf = 0; mf < 4; ++mf)
#pragma unroll
            for (int nf = 0; nf < 4; ++nf) {
                acc[mf][nf] = __builtin_amdgcn_mfma_f32_16x16x32_bf16(ah[mf], bh[nf], acc[mf][nf], 0, 0, 0);
                acc[mf][nf] = __builtin_amdgcn_mfma_f32_16x16x32_bf16(ah[mf], bl[nf], acc[mf][nf], 0, 0, 0);
                acc[mf][nf] = __builtin_amdgcn_mfma_f32_16x16x32_bf16(al[mf], bh[nf], acc[mf][nf], 0, 0, 0);
            }
    }

    float nb[4];
#pragma unroll
    for (int nf = 0; nf < 4; ++nf) nb[nf] = bias[n0 + wn * 64 + nf * 16 + r16];

#pragma unroll
    for (int mf = 0; mf < 4; ++mf)
#pragma unroll
        for (int nf = 0; nf < 4; ++nf)
#pragma unroll
            for (int r = 0; r < 4; ++r) {
                int row = m0 + wm * 64 + mf * 16 + kq * 4 + r;
                int col = n0 + wn * 64 + nf * 16 + r16;
                C[(size_t)row * 384 + col] = acc[mf][nf][r] + nb[nf];
            }
}

// ---------------- GRU macros: single-bf16 h AND single-bf16 whh ----------------
#define GRU_BODY(STCUR, CUR, XR, XZ, XN)                                              \
    {                                                                                 \
        bf16x8 Bh[4];                                                                 \
        _Pragma("unroll")                                                             \
        for (int c = 0; c < 4; ++c) {                                                 \
            int rslot = (b * 128 + 32 * c + 8 * kq) ^ ((b & 7) << 3);                 \
            Bh[c] = *(const bf16x8*)&hb[CUR][rslot];                                  \
        }                                                                             \
        f32x4 acc[3];                                                                 \
        _Pragma("unroll")                                                             \
        for (int g = 0; g < 3; ++g) acc[g] = (f32x4){0.f, 0.f, 0.f, 0.f};             \
        _Pragma("unroll")                                                             \
        for (int c = 0; c < 4; ++c)                                                   \
            _Pragma("unroll")                                                         \
            for (int g = 0; g < 3; ++g)                                               \
                acc[g] = __builtin_amdgcn_mfma_f32_16x16x32_bf16(Ah[g][c], Bh[c], acc[g], 0, 0, 0); \
        f32x4 hnew;                                                                   \
        ushort4 nhi;                                                                  \
        _Pragma("unroll")                                                             \
        for (int r = 0; r < 4; ++r) {                                                 \
            float rr = 1.f / (1.f + __expf(-(XR[r] + acc[0][r] + bh[0][r])));         \
            float zz = 1.f / (1.f + __expf(-(XZ[r] + acc[1][r] + bh[1][r])));         \
            float xa = XN[r] + rr * (acc[2][r] + bh[2][r]);                           \
            float ex = __expf(-2.f * fabsf(xa));                                      \
            float th = (1.f - ex) / (1.f + ex);                                       \
            th = copysignf(th, xa);                                                   \
            hnew[r] = (1.f - zz) * th + zz * hold[r];                                 \
        }                                                                             \
        hold = hnew;                                                                  \
        nhi.x = f2bf(hnew[0]);                                                        \
        nhi.y = f2bf(hnew[1]);                                                        \
        nhi.z = f2bf(hnew[2]);                                                        \
        nhi.w = f2bf(hnew[3]);                                                        \
        *(ushort4*)&hb[(CUR) ^ 1][wslot] = nhi;                                       \
        *(f32x4*)(outp + ((size_t)B * 128 + (STCUR)) * 128 + u0) = hnew;              \
        {                                                                             \
            const int ld = ((STCUR) + 2 < 128) ? (STCUR) + 2 : 127;                   \
            XR = *(const f32x4*)(xb + ld * 384 + u0);                                 \
            XZ = *(const f32x4*)(xb + ld * 384 + 128 + u0);                           \
            XN = *(const f32x4*)(xb + ld * 384 + 256 + u0);                           \
        }                                                                             \
        asm volatile("s_waitcnt lgkmcnt(0)" ::: "memory");                            \
        __builtin_amdgcn_s_barrier();                                                 \
    }

#define GRU_PROLOGUE(BLK, WHI, BHH, XW)                                               \
    const int tid  = threadIdx.x;                                                     \
    const int w    = tid >> 6;                                                        \
    const int lane = tid & 63;                                                        \
    const int b    = lane & 15;                                                       \
    const int kq   = lane >> 4;                                                       \
    const int u0   = 16 * w + 4 * kq;                                                 \
    const int B    = (BLK) * 16 + b;                                                  \
    bf16x8 Ah[3][4];                                                                  \
    _Pragma("unroll")                                                                 \
    for (int g = 0; g < 3; ++g)                                                       \
        _Pragma("unroll")                                                             \
        for (int c = 0; c < 4; ++c) {                                                 \
            size_t off = (size_t)(128 * g + 16 * w + b) * 128 + 32 * c + 8 * kq;      \
            Ah[g][c] = *(const bf16x8*)((WHI) + off);                                 \
        }                                                                             \
    f32x4 bh[3];                                                                      \
    _Pragma("unroll")                                                                 \
    for (int g = 0; g < 3; ++g) bh[g] = *(const f32x4*)((BHH) + 128 * g + u0);        \
    const int wslot = (b * 128 + u0) ^ ((b & 7) << 3);                                \
    *(ushort4*)&hb[0][wslot] = (ushort4){0, 0, 0, 0};                                 \
    __syncthreads();                                                                  \
    f32x4 hold = (f32x4){0.f, 0.f, 0.f, 0.f};                                         \
    const float* xb = (XW) + (size_t)B * 128 * 384;                                   \
    f32x4 xAr = *(const f32x4*)(xb + u0);                                             \
    f32x4 xAz = *(const f32x4*)(xb + 128 + u0);                                       \
    f32x4 xAn = *(const f32x4*)(xb + 256 + u0);                                       \
    f32x4 xBr = *(const f32x4*)(xb + 384 + u0);                                       \
    f32x4 xBz = *(const f32x4*)(xb + 384 + 128 + u0);                                 \
    f32x4 xBn = *(const f32x4*)(xb + 384 + 256 + u0);

// ---------------- GRU layer 1 ----------------
__global__ __launch_bounds__(512, 1) void gru_mfma(const float* __restrict__ xw,
                                                   const unsigned short* __restrict__ whi,
                                                   const float* __restrict__ bhh,
                                                   float* __restrict__ outp)
{
    __shared__ __align__(16) unsigned short hb[2][2048];
    GRU_PROLOGUE(blockIdx.x, whi, bhh, xw)
#pragma unroll 1
    for (int st = 0; st < 128; st += 2) {
        GRU_BODY(st,     0, xAr, xAz, xAn)
        GRU_BODY(st + 1, 1, xBr, xBz, xBn)
    }
}

// ---------------- bodies ----------------
static __device__ __forceinline__ void gate_gemm_body(const float* __restrict__ o,
                                                      const float* __restrict__ gw,
                                                      float* __restrict__ y,
                                                      int gx, int gy, int gz,
                                                      float (*As)[36], float (*Ws)[36])
{
    const int tid = threadIdx.x;
    const int tx = tid & 15, ty = (tid >> 4) & 31;
    const int m0 = gx * 64, n0 = gy * 64;
    const int k0beg = gz * 1024;

    float acc[2][4];
#pragma unroll
    for (int i = 0; i < 2; ++i)
#pragma unroll
        for (int j = 0; j < 4; ++j) acc[i][j] = 0.f;

#pragma unroll 1
    for (int kc = k0beg; kc < k0beg + 1024; kc += 32) {
        {
            int row = tid >> 3;
            int c4  = (tid & 7) * 4;
            int kap = kc + c4;
            int s = kap >> 8, half = (kap >> 7) & 1, h = kap & 127;
            float4 va = *(const float4*)(o + ((size_t)(m0 + row + 256 * half) * 128 + s) * 128 + h);
            *(float4*)&As[row][c4] = va;
            float4 vw = *(const float4*)(gw + (size_t)(n0 + row) * 32768 + kap);
            *(float4*)&Ws[row][c4] = vw;
        }
        __syncthreads();
#pragma unroll 1
        for (int k0 = 0; k0 < 32; k0 += 4) {
            float4 a4[2], w4[4];
#pragma unroll
            for (int i = 0; i < 2; ++i) a4[i] = *(float4*)&As[ty + 32 * i][k0];
#pragma unroll
            for (int j = 0; j < 4; ++j) w4[j] = *(float4*)&Ws[tx + 16 * j][k0];
#pragma unroll
            for (int i = 0; i < 2; ++i)
#pragma unroll
                for (int j = 0; j < 4; ++j) {
                    acc[i][j] += a4[i].x * w4[j].x + a4[i].y * w4[j].y +
                                 a4[i].z * w4[j].z + a4[i].w * w4[j].w;
                }
        }
        __syncthreads();
    }
#pragma unroll
    for (int i = 0; i < 2; ++i)
#pragma unroll
        for (int j = 0; j < 4; ++j) {
            int r = m0 + ty + 32 * i, c = n0 + tx + 16 * j;
            atomicAdd(&y[r * 128 + c], acc[i][j]);
        }
}

static __device__ __forceinline__ void pair_stats_body(const float* __restrict__ o, int s,
                                                       float* __restrict__ bwp,
                                                       float* u2, float* red)
{
    const int tid = threadIdx.x;
    const int h = tid & 127, q = tid >> 7;

    float acc_u = 0.f, acc_sq = 0.f;
    for (int r = 0; r < 128; ++r) {
        int i = q * 128 + r;
        float v = o[((size_t)i * 128 + s) * 128 + h];
        acc_u += v; acc_sq += v * v;
    }
    u2[tid] = acc_u;
    red[tid] = acc_sq;
    __syncthreads();
    for (int st = 256; st > 0; st >>= 1) {
        if (tid < st) red[tid] += red[tid + st];
        __syncthreads();
    }
    float S1 = red[0];
    __syncthreads();
    float uu = 0.f;
    if (tid < 128) {
        float t = u2[tid] + u2[tid + 128] + u2[tid + 256] + u2[tid + 384];
        uu = t * t;
    }
    red[tid] = (tid < 128) ? uu : 0.f;
    __syncthreads();
    for (int st = 64; st > 0; st >>= 1) {
        if (tid < st) red[tid] += red[tid + st];
        __syncthreads();
    }
    if (tid == 0) {
        float S2 = red[0];
        float d2s = 1024.f * S1 - 2.f * S2;
        *bwp = d2s / (512.f * 512.f - 512.f) * 0.25f;
    }
}

static __device__ __forceinline__ void prep_body(const float* __restrict__ o, int s, int l,
                                                 unsigned short* __restrict__ chi,
                                                 unsigned short* __restrict__ clo,
                                                 float* __restrict__ norms)
{
    const int t = threadIdx.x;
    const int h4 = (t & 31) * 4;
    const size_t pb = ((size_t)l * 128 + s) * 512 * 128;
    float* np_ = norms + ((size_t)l * 128 + s) * 512;
#pragma unroll 1
    for (int i = t >> 5; i < 512; i += 16) {
        float4 v = *(const float4*)(o + ((size_t)i * 128 + s) * 128 + h4);
        ushort4 uh, ul;
        uh.x = f2bf(v.x); ul.x = f2bf(v.x - bf2f(uh.x));
        uh.y = f2bf(v.y); ul.y = f2bf(v.y - bf2f(uh.y));
        uh.z = f2bf(v.z); ul.z = f2bf(v.z - bf2f(uh.z));
        uh.w = f2bf(v.w); ul.w = f2bf(v.w - bf2f(uh.w));
        *(ushort4*)(chi + pb + (size_t)i * 128 + h4) = uh;
        *(ushort4*)(clo + pb + (size_t)i * 128 + h4) = ul;
        float sq = v.x * v.x + v.y * v.y + v.z * v.z + v.w * v.w;
        sq += __shfl_xor(sq, 1);
        sq += __shfl_xor(sq, 2);
        sq += __shfl_xor(sq, 4);
        sq += __shfl_xor(sq, 8);
        sq += __shfl_xor(sq, 16);
        if ((t & 31) == 0) np_[i] = sq;
    }
}

static __device__ __forceinline__ void fc_body(int bid0, const float* __restrict__ o2,
                                               const float* __restrict__ fcw,
                                               const float* __restrict__ fcb,
                                               float* __restrict__ outp)
{
    int gid = bid0 * 512 + threadIdx.x;
    if (gid < 3072) {
        int b = gid / 6, oo = gid - b * 6;
        const float* xr = o2 + ((size_t)b * 128 + 127) * 128;
        const float* wr = fcw + oo * 128;
        float acc = fcb[oo];
#pragma unroll 16
        for (int k = 0; k < 128; ++k) acc += xr[k] * wr[k];
        outp[gid] = acc;
    }
}

// mmd with LDS-staged panels: [128][40] ushort (80B stride: 16B-aligned b128,
// 2-way banks = free). Coalesced global loads replace scattered frag loads.
static __device__ __forceinline__ void mmd_body(const unsigned short* __restrict__ chi,
                                                const unsigned short* __restrict__ clo,
                                                const float* __restrict__ norms,
                                                const float* __restrict__ bw,
                                                float* __restrict__ mmdv,
                                                int p, int tp, float* rbuf,
                                                unsigned short (*Ash)[40], unsigned short (*Asl)[40],
                                                unsigned short (*Bsh)[40], unsigned short (*Bsl)[40])
{
    int ti, tj;
    if (tp < 4)      { ti = 0; tj = tp; }
    else if (tp < 7) { ti = 1; tj = tp - 3; }
    else if (tp < 9) { ti = 2; tj = tp - 5; }
    else             { ti = 3; tj = 3; }
    const float sgn  = ((ti < 2) == (tj < 2)) ? 1.f : -1.f;
    const float coef = sgn * ((ti == tj) ? 1.f : 2.f);

    const int tid  = threadIdx.x;
    const int lane = tid & 63;
    const int wave = tid >> 6;
    const int wm = wave >> 1, wn = wave & 1;
    const int r16 = lane & 15;
    const int kq  = lane >> 4;

    const size_t pbase = (size_t)p * 512 * 128;
    const size_t abase = pbase + (size_t)(ti * 128) * 128;
    const size_t bbase = pbase + (size_t)(tj * 128) * 128;

    const int srow = tid >> 1;            // staging row 0..127
    const int scol = (tid & 1) * 16;      // staging col 0 or 16

    f32x4 acc[4][4];
#pragma unroll
    for (int mf = 0; mf < 4; ++mf)
#pragma unroll
        for (int nf = 0; nf < 4; ++nf) acc[mf][nf] = (f32x4){0.f, 0.f, 0.f, 0.f};

#pragma unroll 1
    for (int kc = 0; kc < 128; kc += 32) {
        // coalesced panel loads (issue before barrier so they overlap the wait)
        const size_t ga = abase + (size_t)srow * 128 + kc + scol;
        const size_t gb = bbase + (size_t)srow * 128 + kc + scol;
        bf16x8 ah0 = *(const bf16x8*)(chi + ga);
        bf16x8 ah1 = *(const bf16x8*)(chi + ga + 8);
        bf16x8 al0 = *(const bf16x8*)(clo + ga);
        bf16x8 al1 = *(const bf16x8*)(clo + ga + 8);
        bf16x8 bh0 = *(const bf16x8*)(chi + gb);
        bf16x8 bh1 = *(const bf16x8*)(chi + gb + 8);
        bf16x8 bl0 = *(const bf16x8*)(clo + gb);
        bf16x8 bl1 = *(const bf16x8*)(clo + gb + 8);
        __syncthreads();                 // prev iter's frag reads complete
        *(bf16x8*)&Ash[srow][scol]     = ah0;
        *(bf16x8*)&Ash[srow][scol + 8] = ah1;
        *(bf16x8*)&Asl[srow][scol]     = al0;
        *(bf16x8*)&Asl[srow][scol + 8] = al1;
        *(bf16x8*)&Bsh[srow][scol]     = bh0;
        *(bf16x8*)&Bsh[srow][scol + 8] = bh1;
        *(bf16x8*)&Bsl[srow][scol]     = bl0;
        *(bf16x8*)&Bsl[srow][scol + 8] = bl1;
        __syncthreads();

        bf16x8 ah[4], al[4], bh[4], bl[4];
#pragma unroll
        for (int mf = 0; mf < 4; ++mf) {
            int r = wm * 64 + mf * 16 + r16;
            ah[mf] = *(const bf16x8*)&Ash[r][8 * kq];
            al[mf] = *(const bf16x8*)&Asl[r][8 * kq];
        }
#pragma unroll
        for (int nf = 0; nf < 4; ++nf) {
            int r = wn * 64 + nf * 16 + r16;
            bh[nf] = *(const bf16x8*)&Bsh[r][8 * kq];
            bl[nf] = *(const bf16x8*)&Bsl[r][8 * kq];
        }
#pragma unroll
        for (int mf = 0; mf < 4; ++mf)
#pragma unroll
            for (int nf = 0; nf < 4; ++nf) {
                acc[mf][nf] = __builtin_amdgcn_mfma_f32_16x16x32_bf16(ah[mf], bh[nf], acc[mf][nf], 0, 0, 0);
                acc[mf][nf] = __builtin_amdgcn_mfma_f32_16x16x32_bf16(ah[mf], bl[nf], acc[mf][nf], 0, 0, 0);
                acc[mf][nf] = __builtin_amdgcn_mfma_f32_16x16x32_bf16(al[mf], bh[nf], acc[mf][nf], 0, 0, 0);
            }
    }

    const float* np_ = norms + (size_t)p * 512;
    float na[4][4], nb[4];
#pragma unroll
    for (int mf = 0; mf < 4; ++mf)
#pragma unroll
        for (int r = 0; r < 4; ++r)
            na[mf][r] = np_[ti * 128 + wm * 64 + mf * 16 + (lane >> 4) * 4 + r];
#pragma unroll
    for (int nf = 0; nf < 4; ++nf)
        nb[nf] = np_[tj * 128 + wn * 64 + nf * 16 + (lane & 15)];

    const float bwv = bw[p];
    const float c4 = -1.f / (bwv * 16.f);
    float tot = 0.f;
#pragma unroll
    for (int mf = 0; mf < 4; ++mf)
#pragma unroll
        for (int nf = 0; nf < 4; ++nf)
#pragma unroll
            for (int r = 0; r < 4; ++r) {
                float d2 = na[mf][r] + nb[nf] - 2.f * acc[mf][nf][r];
                float e4 = __expf(c4 * d2);
                float e3 = e4 * e4;
                float e2 = e3 * e3;
                float e1 = e2 * e2;
                float e0 = e1 * e1;
                tot += ((e0 + e1) + (e2 + e3)) + e4;
            }
    tot *= coef;

    for (int off = 32; off > 0; off >>= 1) tot += __shfl_down(tot, off);
    if ((tid & 63) == 0) rbuf[tid >> 6] = tot;
    __syncthreads();
    if (tid == 0) atomicAdd(&mmdv[p], rbuf[0] + rbuf[1] + rbuf[2] + rbuf[3]);
}

static __device__ __forceinline__ void gate_reduce_body(const float* __restrict__ y,
                                                        const float* __restrict__ gamma,
                                                        const float* __restrict__ beta,
                                                        float* __restrict__ ws_p,
                                                        float* __restrict__ out_p,
                                                        float* red)
{
    const int o = threadIdx.x;
    const bool act = (o < 128);
    float wo = 0.f;
    if (act) {
        float sum = 0.f, sumsq = 0.f;
        for (int b = 0; b < 256; ++b) {
            float v = y[b * 128 + o];
            sum += v; sumsq += v * v;
        }
        float m = sum * (1.f / 256.f);
        float var = sumsq * (1.f / 256.f) - m * m;
        float inv = rsqrtf(var + 1e-5f);
        float g = gamma[o], be = beta[o];
        float sw = 0.f;
        for (int b = 0; b < 256; ++b) {
            float v = y[b * 128 + o];
            float t = g * (v - m) * inv + be;
            sw += 1.f / (1.f + __expf(-t));
        }
        wo = sw * (1.f / 256.f);
        red[o] = wo;
    }
    __syncthreads();
    for (int st = 64; st > 0; st >>= 1) {
        if (act && o < st) red[o] = fmaxf(red[o], red[o + st]);
        __syncthreads();
    }
    float mx = red[0];
    __syncthreads();
    float e = act ? __expf(wo - mx) : 0.f;
    if (act) red[o] = e;
    __syncthreads();
    for (int st = 64; st > 0; st >>= 1) {
        if (act && o < st) red[o] += red[o + st];
        __syncthreads();
    }
    if (act) {
        float r = e / red[0];
        ws_p[o] = r;
        out_p[o] = r;
    }
}

// ---------------- FAT1: gru2 (0..31, prio 1) || gate_gemm0 (32..287) || pair_stats l0 (288..415) ----------------
// Launched with 56 KB dynamic LDS -> total 88 KB/block -> 1 block/CU (private gru CUs)
__global__ __launch_bounds__(512, 1) void fat1(const float* __restrict__ xw,
                                               const unsigned short* __restrict__ whi,
                                               const float* __restrict__ bhh,
                                               float* __restrict__ o2,
                                               const float* __restrict__ o1,
                                               const float* __restrict__ gw0,
                                               float* __restrict__ y0,
                                               float* __restrict__ bw)
{
    __shared__ __align__(16) unsigned short hb[2][2048];
    __shared__ __align__(16) float As[64][36];
    __shared__ __align__(16) float Ws[64][36];
    __shared__ float u2s[512];
    __shared__ float reds[512];

    const int bid = blockIdx.x;
    if (bid < 32) {
        __builtin_amdgcn_s_setprio(1);
        float* outp = o2;
        GRU_PROLOGUE(bid, whi, bhh, xw)
#pragma unroll 1
        for (int st = 0; st < 128; st += 2) {
            GRU_BODY(st,     0, xAr, xAz, xAn)
            GRU_BODY(st + 1, 1, xBr, xBz, xBn)
        }
        __builtin_amdgcn_s_setprio(0);
    } else if (bid < 288) {
        int g = bid - 32;
        gate_gemm_body(o1, gw0, y0, g & 3, (g >> 2) & 1, g >> 3, As, Ws);
    } else {
        int s = bid - 288;
        pair_stats_body(o1, s, &bw[s], u2s, reds);
    }
}

// ---------------- FAT2: gate_gemm1 (0..255) || pair_stats l1 (256..383) || fc (384..389) || prep (390..645) ----------------
__global__ __launch_bounds__(512, 1) void fat2(const float* __restrict__ o2,
                                               const float* __restrict__ gw1,
                                               float* __restrict__ y1,
                                               float* __restrict__ bw,
                                               const float* __restrict__ fcw,
                                               const float* __restrict__ fcb,
                                               float* __restrict__ outp,
                                               const float* __restrict__ o1,
                                               unsigned short* __restrict__ chi,
                                               unsigned short* __restrict__ clo,
                                               float* __restrict__ norms)
{
    __shared__ __align__(16) float As[64][36];
    __shared__ __align__(16) float Ws[64][36];
    __shared__ float u2s[512];
    __shared__ float reds[512];

    const int bid = blockIdx.x;
    if (bid < 256) {
        gate_gemm_body(o2, gw1, y1, bid & 3, (bid >> 2) & 1, bid >> 3, As, Ws);
    } else if (bid < 384) {
        int s = bid - 256;
        pair_stats_body(o2, s, &bw[128 + s], u2s, reds);
    } else if (bid < 390) {
        fc_body(bid - 384, o2, fcw, fcb, outp);
    } else {
        int idx = bid - 390;
        int s = idx & 127, l = idx >> 7;
        prep_body(l ? o2 : o1, s, l, chi, clo, norms);
    }
}

// ---------------- mmd tail: 2560 mmd (LDS-staged) + gate_reduce x2 ----------------
__global__ __launch_bounds__(256) void mmd_tail(const unsigned short* __restrict__ chi,
                                                const unsigned short* __restrict__ clo,
                                                const float* __restrict__ norms,
                                                const float* __restrict__ bw,
                                                float* __restrict__ mmdv,
                                                const float* __restrict__ y0, const float* __restrict__ y1,
                                                const float* __restrict__ g0, const float* __restrict__ b0,
                                                const float* __restrict__ g1, const float* __restrict__ b1,
                                                float* __restrict__ wts_ws, float* __restrict__ wts_out)
{
    __shared__ float rbuf[4];
    __shared__ float red[128];
    __shared__ __align__(16) unsigned short Ash[128][40];
    __shared__ __align__(16) unsigned short Asl[128][40];
    __shared__ __align__(16) unsigned short Bsh[128][40];
    __shared__ __align__(16) unsigned short Bsl[128][40];

    const int lin = blockIdx.x;
    if (lin < 2560) {
        const int v = (lin & 7) * 320 + (lin >> 3);
        mmd_body(chi, clo, norms, bw, mmdv, v / 10, v % 10, rbuf, Ash, Asl, Bsh, Bsl);
    } else {
        int which = lin - 2560;
        gate_reduce_body(which ? y1 : y0, which ? g1 : g0, which ? b1 : b0,
                         wts_ws + which * 128, wts_out + which * 128, red);
    }
}

// ---------------- final loss ----------------
__global__ void final_loss(const float* __restrict__ wts,
                           const float* __restrict__ mmdv,
                           float* __restrict__ out)
{
    const int t = threadIdx.x;
    float v = wts[t] * mmdv[t];
    __shared__ float red[256];
    red[t] = v;
    __syncthreads();
    for (int st = 128; st > 0; st >>= 1) {
        if (t < st) red[t] += red[t + st];
        __syncthreads();
    }
    if (t == 0) out[0] = red[0] * (1.f / 65536.f);
}

// ---------------- launch ----------------
extern "C" void kernel_launch(void* const* d_in, const int* in_sizes, int n_in,
                              void* d_out, int out_size, void* d_ws, size_t ws_size,
                              hipStream_t stream)
{
    (void)in_sizes; (void)n_in; (void)out_size; (void)ws_size;
    const float* x    = (const float*)d_in[0];
    const float* wih0 = (const float*)d_in[1];
    const float* whh0 = (const float*)d_in[2];
    const float* bih0 = (const float*)d_in[3];
    const float* bhh0 = (const float*)d_in[4];
    const float* wih1 = (const float*)d_in[5];
    const float* whh1 = (const float*)d_in[6];
    const float* bih1 = (const float*)d_in[7];
    const float* bhh1 = (const float*)d_in[8];
    const float* gw0  = (const float*)d_in[9];
    const float* bg0  = (const float*)d_in[11];
    const float* bb0  = (const float*)d_in[12];
    const float* gw1  = (const float*)d_in[13];
    const float* bg1  = (const float*)d_in[15];
    const float* bb1  = (const float*)d_in[16];
    const float* fcw  = (const float*)d_in[17];
    const float* fcb  = (const float*)d_in[18];

    float* out = (float*)d_out;
    char*  ws  = (char*)d_ws;
    float* xw   = (float*)(ws + XW_OFF);
    float* o1   = (float*)(ws + O1_OFF);
    float* o2   = (float*)(ws + O2_OFF);
    float* y0   = (float*)(ws + Y0_OFF);
    float* y1   = (float*)(ws + Y1_OFF);
    float* mmdv = (float*)(ws + MMD_OFF);
    float* wts  = (float*)(ws + WTS_OFF);
    float* bwv  = (float*)(ws + BW_OFF);
    float* nrm  = (float*)(ws + NRM_OFF);
    unsigned short* chi  = (unsigned short*)(ws + CHI_OFF);
    unsigned short* clo  = (unsigned short*)(ws + CLO_OFF);
    unsigned short* whi0 = (unsigned short*)(ws + WBF_OFF);
    unsigned short* wlo0 = whi0 + 49152;
    unsigned short* whi1 = wlo0 + 49152;
    unsigned short* wlo1 = whi1 + 49152;
    unsigned short* hhi0 = wlo1 + 49152;
    unsigned short* hlo0 = hhi0 + 49152;
    unsigned short* hhi1 = hlo0 + 49152;
    unsigned short* hlo1 = hhi1 + 49152;

    hipMemsetAsync(y0, 0, (256 * 128 * 2 + 256) * sizeof(float), stream);

    cvt_w4<<<dim3(48, 4), 256, 0, stream>>>(wih0, wih1, whh0, whh1,
                                            whi0, wlo0, whi1, wlo1,
                                            hhi0, hlo0, hhi1, hlo1);

    gemm_f32a<<<dim3(512, 3), 256, 0, stream>>>(x, whi0, wlo0, bih0, xw);
    gru_mfma<<<32, 512, 0, stream>>>(xw, hhi0, bhh0, o1);
    gemm_f32a<<<dim3(512, 3), 256, 0, stream>>>(o1, whi1, wlo1, bih1, xw);

    // 56 KB dynamic LDS: total 88 KB/block -> hard 1 block/CU
    fat1<<<416, 512, 56 * 1024, stream>>>(xw, hhi1, bhh1, o2, o1, gw0, y0, bwv);
    fat2<<<646, 512, 0, stream>>>(o2, gw1, y1, bwv, fcw, fcb, out, o1, chi, clo, nrm);

    mmd_tail<<<2562, 256, 0, stream>>>(chi, clo, nrm, bwv, mmdv,
                                       y0, y1, bg0, bb0, bg1, bb1, wts, out + 3073);

    final_loss<<<1, 256, 0, stream>>>(wts, mmdv, out + 3072);
}